// Round 3
// baseline (755.460 us; speedup 1.0000x reference)
//
#include <hip/hip_runtime.h>

#define B_TOT 1024
#define T_STEPS 24
#define F 64          // FILTERS
#define C2 128        // 2*FILTERS
#define FEAT 15
#define L_ENC 168
#define HID 128
#define K5 384        // N_DIL*FILTERS
#define R 4           // batch rows per block
#define BLK 512

__device__ __forceinline__ float rl(float v, int l) {
  return __uint_as_float(__builtin_amdgcn_readlane(__float_as_uint(v), (unsigned)l));
}
__device__ __forceinline__ float sigmoidf_(float x) { return 1.0f / (1.0f + expf(-x)); }

// Wave layout: 8 waves/block. wave w = (r = w>>1, h = w&1).
// Lane c' of wave (r,h) owns output column cg = h*64 + c' of the 128-wide matmuls,
// and holds activation channel c' of row r in a register (broadcast via v_readlane).
// Weights live in VGPRs (per-lane column slices) -> zero LDS in the FMA loops.
//
// amdgpu_waves_per_eu(2,2): pin MAX waves/EU to 2 so the allocator gets the
// full 256-VGPR budget. (launch_bounds' 2nd arg is only a MINIMUM — round 2
// showed the compiler picking 128 VGPRs / 4 waves and spilling the weight
// arrays to scratch: WRITE_SIZE 5.2 MB, dur 455 us.) Grid = 1 block/CU, so
// occupancy >2 waves/SIMD is worthless here anyway.
__global__ __attribute__((amdgpu_flat_work_group_size(BLK, BLK), amdgpu_waves_per_eu(2, 2)))
void decoder_v4_kernel(
    const float* __restrict__ dec_feat,   // (B,24,15)
    const float* __restrict__ dec_init,   // (B,1)
    const float* __restrict__ enc,        // (6,B,168,64)
    const float* __restrict__ gW1, const float* __restrict__ gb1,
    const float* __restrict__ gW2, const float* __restrict__ gb2,
    const float* __restrict__ gW3,
    const float* __restrict__ gW4, const float* __restrict__ gb4,
    const float* __restrict__ gW5, const float* __restrict__ gb5,
    const float* __restrict__ gW6, const float* __restrict__ gb6,
    float* __restrict__ out)              // (B,24)
{
  __shared__ float ring[7936];            // layers d=1,2,4,8,16; base = 256*(d-1), slot stride 256
  __shared__ float skipbuf[R][K5];        // 6 KB
  __shared__ float fbuf[R][F], gbuf[R][F];
  __shared__ float xbuf[R][F];
  __shared__ float2 P2[8][R][F];          // W5 partials: [wave][row][lane] -> (col lane, col lane+64)
  __shared__ float sb5[HID], sW6[HID];
  __shared__ float prevy[R];
  __shared__ float wsum[8];
  __shared__ float sb6v;

  const int tid  = threadIdx.x;
  const int wv   = tid >> 6;       // 0..7
  const int lane = tid & 63;
  const int r    = wv >> 1;        // row 0..3
  const int h    = wv & 1;         // column half
  const int cg   = h * F + lane;   // output column 0..127
  const int b0   = blockIdx.x * R;

  // ---- persistent per-lane weight columns (VGPRs) ----
  float w1c[16], w2c[F], w3c[F], w4c[F];
  #pragma unroll
  for (int k = 0; k < 16; ++k) w1c[k] = gW1[k * F + lane];
  #pragma unroll
  for (int k = 0; k < F; ++k)  w2c[k] = gW2[k * C2 + cg];
  #pragma unroll
  for (int k = 0; k < F; ++k)  w3c[k] = gW3[k * C2 + cg];
  #pragma unroll
  for (int k = 0; k < F; ++k)  w4c[k] = gW4[k * C2 + cg];
  const float b1c = gb1[lane];
  const float b2c = gb2[cg];
  const float b4c = gb4[cg];

  if (tid < R) prevy[tid] = dec_init[b0 + tid];
  if (tid < HID) sb5[tid] = gb5[tid];
  else if (tid < 2 * HID) sW6[tid - HID] = gW6[tid - HID];
  if (tid == 0) sb6v = gb6[0];
  __syncthreads();

  for (int t = 0; t < T_STEPS; ++t) {
    // ---- cur + W1: x[r][lane] = tanh(sum_k cur[k]*W1[k][lane] + b1) (both waves redundantly) ----
    float curv = 0.0f;
    if (lane == 0) curv = prevy[r];
    else if (lane < 16) curv = dec_feat[(b0 + r) * (T_STEPS * FEAT) + t * FEAT + (lane - 1)];
    float acc1 = b1c;
    #pragma unroll
    for (int k = 0; k < 16; ++k) acc1 = fmaf(rl(curv, k), w1c[k], acc1);
    float x = tanhf(acc1);

    // stat for dilation 0 (d=1)
    float stat;
    if (t >= 1) stat = ring[r * F + lane];  // base 0, slot 0
    else        stat = enc[((size_t)(b0 + r) * L_ENC + (L_ENC + t - 1)) * F + lane];

    // ---- dilation stack ----
    for (int i = 0; i < 6; ++i) {
      const int d = 1 << i;
      // phase A: dilated[r][cg] = b2 + stat@W2 + x@W3   (pure VALU)
      float accS = b2c, accI = 0.0f;
      #pragma unroll
      for (int k = 0; k < F; ++k) {
        accS = fmaf(rl(stat, k), w2c[k], accS);
        accI = fmaf(rl(x, k),    w3c[k], accI);
      }
      const float dil = accS + accI;
      if (h == 0) fbuf[r][lane] = dil;
      else        gbuf[r][lane] = dil;

      // prefetch next dilation's state while the bounce settles
      float stat_n = 0.0f;
      if (i < 5) {
        const int d2 = d << 1;
        if (t >= d2)
          stat_n = ring[256 * (d2 - 1) + (t & (d2 - 1)) * (R * F) + r * F + lane];
        else
          stat_n = enc[((size_t)((i + 1) * B_TOT + b0 + r) * L_ENC + (L_ENC + t - d2)) * F + lane];
      }
      __syncthreads();

      const float fv = (h == 0) ? dil : fbuf[r][lane];
      const float gv = (h == 0) ? gbuf[r][lane] : dil;
      const float gated = tanhf(fv) * sigmoidf_(gv);

      // phase B: out[r][cg] = gated @ W4 + b4   (pure VALU)
      float accB = b4c;
      #pragma unroll
      for (int k = 0; k < F; ++k) accB = fmaf(rl(gated, k), w4c[k], accB);

      if (h == 0) {
        skipbuf[r][i * F + lane] = fmaxf(accB, 0.0f);   // skip (cols 0..63)
      } else {
        x += accB;                                      // residual (cols 64..127)
        xbuf[r][lane] = x;
        if (i < 5) ring[256 * (d - 1) + (t & (d - 1)) * (R * F) + r * F + lane] = x;
      }
      __syncthreads();
      if (h == 0) x = xbuf[r][lane];
      stat = stat_n;
    }

    // ---- W5: h = relu(skip @ W5 + b5); k-split mod-8 across waves (W5 read once/CU) ----
    float vsk0, vsk1, vsk2, vsk3;
    {
      int kk = wv + 8 * lane;            // lane l holds skip[.][wv+8l] (l<48 valid)
      int kkc = kk < K5 ? kk : 0;
      vsk0 = skipbuf[0][kkc]; vsk1 = skipbuf[1][kkc];
      vsk2 = skipbuf[2][kkc]; vsk3 = skipbuf[3][kkc];
    }
    float a00 = 0, a01 = 0, a10 = 0, a11 = 0, a20 = 0, a21 = 0, a30 = 0, a31 = 0;
    const float* w5p = gW5 + (size_t)wv * HID + lane;
    #pragma unroll 4
    for (int j = 0; j < 48; ++j) {
      const float wa = w5p[0];
      const float wb = w5p[64];
      const float s0 = rl(vsk0, j), s1 = rl(vsk1, j), s2 = rl(vsk2, j), s3 = rl(vsk3, j);
      a00 = fmaf(s0, wa, a00); a01 = fmaf(s0, wb, a01);
      a10 = fmaf(s1, wa, a10); a11 = fmaf(s1, wb, a11);
      a20 = fmaf(s2, wa, a20); a21 = fmaf(s2, wb, a21);
      a30 = fmaf(s3, wa, a30); a31 = fmaf(s3, wb, a31);
      w5p += 8 * HID;
    }
    P2[wv][0][lane] = make_float2(a00, a01);
    P2[wv][1][lane] = make_float2(a10, a11);
    P2[wv][2][lane] = make_float2(a20, a21);
    P2[wv][3][lane] = make_float2(a30, a31);
    __syncthreads();

    // ---- finalize h, then y = h @ W6 + b6 ----
    {
      const int rr = tid >> 7;          // 0..3
      const int cc = tid & 127;         // wave-uniform half: cc>>6 constant per wave
      const int ll = cc & 63;
      float s = sb5[cc];
      if ((cc >> 6) == 0) {
        #pragma unroll
        for (int w8 = 0; w8 < 8; ++w8) s += P2[w8][rr][ll].x;
      } else {
        #pragma unroll
        for (int w8 = 0; w8 < 8; ++w8) s += P2[w8][rr][ll].y;
      }
      const float hv = fmaxf(s, 0.0f);
      float v = hv * sW6[cc];
      #pragma unroll
      for (int off = 32; off >= 1; off >>= 1) v += __shfl_xor(v, off);
      if ((tid & 63) == 0) wsum[tid >> 6] = v;
    }
    __syncthreads();
    if (tid < R) {
      const float y = wsum[2 * tid] + wsum[2 * tid + 1] + sb6v;
      prevy[tid] = y;
      out[(b0 + tid) * T_STEPS + t] = y;
    }
    __syncthreads();
  }
}

extern "C" void kernel_launch(void* const* d_in, const int* in_sizes, int n_in,
                              void* d_out, int out_size, void* d_ws, size_t ws_size,
                              hipStream_t stream) {
  const float* dec_feat = (const float*)d_in[0];
  const float* dec_init = (const float*)d_in[1];
  const float* enc      = (const float*)d_in[2];
  const float* W1 = (const float*)d_in[3];
  const float* b1 = (const float*)d_in[4];
  const float* W2 = (const float*)d_in[5];
  const float* b2 = (const float*)d_in[6];
  const float* W3 = (const float*)d_in[7];
  const float* W4 = (const float*)d_in[8];
  const float* b4 = (const float*)d_in[9];
  const float* W5 = (const float*)d_in[10];
  const float* b5 = (const float*)d_in[11];
  const float* W6 = (const float*)d_in[12];
  const float* b6 = (const float*)d_in[13];
  float* out = (float*)d_out;

  dim3 grid(B_TOT / R);
  dim3 block(BLK);
  decoder_v4_kernel<<<grid, block, 0, stream>>>(
      dec_feat, dec_init, enc, W1, b1, W2, b2, W3, W4, b4, W5, b5, W6, b6, out);
}

// Round 4
// 702.287 us; speedup vs baseline: 1.0757x; 1.0757x over previous
//
#include <hip/hip_runtime.h>

#define B_TOT 1024
#define T_STEPS 24
#define F 64          // FILTERS
#define C2 128        // 2*FILTERS
#define FEAT 15
#define L_ENC 168
#define HID 128
#define K5 384        // N_DIL*FILTERS
#define R 4           // batch rows per block
#define BLK 512

__device__ __forceinline__ float rl(float v, int l) {
  return __uint_as_float(__builtin_amdgcn_readlane(__float_as_uint(v), (unsigned)l));
}
__device__ __forceinline__ float sigmoidf_(float x) { return 1.0f / (1.0f + expf(-x)); }

// v5: fit-in-128-VGPR design (rounds 2/3 proved 208 persistent regs => spills).
//  - W2 column slice in VGPRs (64 regs), W3/W4 transposed in LDS, streamed as
//    ds_read_b128 (stride 68 floats = 17 float4 -> odd-mod-8 bank-group spread).
//  - W1 in LDS (b128, once per step). W5 from global (L2-hot), with skip
//    activations broadcast from LDS (skipT) instead of readlane.
//  - Activations broadcast via v_readlane as before.
__global__ __launch_bounds__(BLK) void decoder_v5_kernel(
    const float* __restrict__ dec_feat,   // (B,24,15)
    const float* __restrict__ dec_init,   // (B,1)
    const float* __restrict__ enc,        // (6,B,168,64)
    const float* __restrict__ gW1, const float* __restrict__ gb1,
    const float* __restrict__ gW2, const float* __restrict__ gb2,
    const float* __restrict__ gW3,
    const float* __restrict__ gW4, const float* __restrict__ gb4,
    const float* __restrict__ gW5, const float* __restrict__ gb5,
    const float* __restrict__ gW6, const float* __restrict__ gb6,
    float* __restrict__ out)              // (B,24)
{
  __shared__ float  ring[7936];           // layers d=1,2,4,8,16; base 256*(d-1), slot stride 256
  __shared__ float4 sW3T[C2 * 17];        // [cg][k4]: row stride 68 floats (padded)
  __shared__ float4 sW4T[C2 * 17];
  __shared__ float  sW1T[F * 20];         // [lane][k]: stride 20 floats
  __shared__ float  skipT[8][R][48];      // skip[r][kk] at [kk&7][r][kk>>3]
  __shared__ float  fbuf[R][F], gbuf[R][F], xbuf[R][F];
  __shared__ float2 P2[8][R][F];          // W5 partials
  __shared__ float  sb5[HID], sW6[HID];
  __shared__ float  prevy[R];
  __shared__ float  wsum[8];
  __shared__ float  sb6v;

  const int tid  = threadIdx.x;
  const int wv   = tid >> 6;       // 0..7
  const int lane = tid & 63;
  const int r    = wv >> 1;        // row 0..3
  const int h    = wv & 1;         // column half
  const int cg   = h * F + lane;   // output column 0..127
  const int b0   = blockIdx.x * R;

  // ---- stage weights ----
  float* w3f = (float*)sW3T;
  float* w4f = (float*)sW4T;
  for (int i = tid; i < C2 * F; i += BLK) {
    int cc = i & 127, kk = i >> 7;                 // coalesced global reads
    w3f[cc * 68 + kk] = gW3[kk * C2 + cc];
    w4f[cc * 68 + kk] = gW4[kk * C2 + cc];
  }
  for (int i = tid; i < F * 16; i += BLK) {
    int ll = i & 63, kk = i >> 6;
    sW1T[ll * 20 + kk] = gW1[kk * F + ll];
  }
  float w2c[F];                                    // persistent, 64 VGPRs
  #pragma unroll
  for (int k = 0; k < F; ++k) w2c[k] = gW2[k * C2 + cg];
  const float b1c = gb1[lane];
  const float b2c = gb2[cg];
  const float b4c = gb4[cg];

  if (tid < R) prevy[tid] = dec_init[b0 + tid];
  if (tid < HID) sb5[tid] = gb5[tid];
  else if (tid < 2 * HID) sW6[tid - HID] = gW6[tid - HID];
  if (tid == 0) sb6v = gb6[0];
  __syncthreads();

  for (int t = 0; t < T_STEPS; ++t) {
    // ---- W1: x = tanh(cur @ W1 + b1), both halves redundantly ----
    float curv = 0.0f;
    if (lane == 0) curv = prevy[r];
    else if (lane < 16) curv = dec_feat[(b0 + r) * (T_STEPS * FEAT) + t * FEAT + (lane - 1)];
    float acc1 = b1c;
    const float4* w1p = (const float4*)&sW1T[lane * 20];
    #pragma unroll
    for (int k4 = 0; k4 < 4; ++k4) {
      float4 wv4 = w1p[k4];
      acc1 = fmaf(rl(curv, 4 * k4 + 0), wv4.x, acc1);
      acc1 = fmaf(rl(curv, 4 * k4 + 1), wv4.y, acc1);
      acc1 = fmaf(rl(curv, 4 * k4 + 2), wv4.z, acc1);
      acc1 = fmaf(rl(curv, 4 * k4 + 3), wv4.w, acc1);
    }
    float x = tanhf(acc1);

    // stat for dilation 0 (d=1)
    float stat;
    if (t >= 1) stat = ring[r * F + lane];
    else        stat = enc[((size_t)(b0 + r) * L_ENC + (L_ENC + t - 1)) * F + lane];

    // ---- dilation stack ----
    for (int i = 0; i < 6; ++i) {
      const int d = 1 << i;
      // phase A: dil = b2 + stat@W2 (regs) + x@W3 (LDS b128)
      float accS = b2c, accI = 0.0f;
      const float4* w3p = &sW3T[cg * 17];
      #pragma unroll
      for (int k4 = 0; k4 < 16; ++k4) {
        float4 w3v = w3p[k4];
        const int kb = 4 * k4;
        accS = fmaf(rl(stat, kb + 0), w2c[kb + 0], accS);
        accI = fmaf(rl(x,    kb + 0), w3v.x,       accI);
        accS = fmaf(rl(stat, kb + 1), w2c[kb + 1], accS);
        accI = fmaf(rl(x,    kb + 1), w3v.y,       accI);
        accS = fmaf(rl(stat, kb + 2), w2c[kb + 2], accS);
        accI = fmaf(rl(x,    kb + 2), w3v.z,       accI);
        accS = fmaf(rl(stat, kb + 3), w2c[kb + 3], accS);
        accI = fmaf(rl(x,    kb + 3), w3v.w,       accI);
      }
      const float dil = accS + accI;
      if (h == 0) fbuf[r][lane] = dil;
      else        gbuf[r][lane] = dil;

      // prefetch next dilation's state
      float stat_n = 0.0f;
      if (i < 5) {
        const int d2 = d << 1;
        if (t >= d2)
          stat_n = ring[256 * (d2 - 1) + (t & (d2 - 1)) * (R * F) + r * F + lane];
        else
          stat_n = enc[((size_t)((i + 1) * B_TOT + b0 + r) * L_ENC + (L_ENC + t - d2)) * F + lane];
      }
      __syncthreads();

      const float fv = (h == 0) ? dil : fbuf[r][lane];
      const float gv = (h == 0) ? gbuf[r][lane] : dil;
      const float gated = tanhf(fv) * sigmoidf_(gv);

      // phase B: o = gated @ W4 (LDS b128) + b4
      float accB0 = b4c, accB1 = 0.0f;
      const float4* w4p = &sW4T[cg * 17];
      #pragma unroll
      for (int k4 = 0; k4 < 16; ++k4) {
        float4 w4v = w4p[k4];
        const int kb = 4 * k4;
        accB0 = fmaf(rl(gated, kb + 0), w4v.x, accB0);
        accB1 = fmaf(rl(gated, kb + 1), w4v.y, accB1);
        accB0 = fmaf(rl(gated, kb + 2), w4v.z, accB0);
        accB1 = fmaf(rl(gated, kb + 3), w4v.w, accB1);
      }
      const float o = accB0 + accB1;
      if (h == 0) {
        // skip kk = i*64+lane -> skipT[kk&7][r][kk>>3]
        skipT[lane & 7][r][i * 8 + (lane >> 3)] = fmaxf(o, 0.0f);
      } else {
        x += o;
        xbuf[r][lane] = x;
        if (i < 5) ring[256 * (d - 1) + (t & (d - 1)) * (R * F) + r * F + lane] = x;
      }
      __syncthreads();
      if (h == 0) x = xbuf[r][lane];
      stat = stat_n;
    }

    // ---- W5: k-split mod-8 across waves; skip via LDS broadcast b128 ----
    float a00 = 0, a01 = 0, a10 = 0, a11 = 0, a20 = 0, a21 = 0, a30 = 0, a31 = 0;
    const float* w5p = gW5 + (size_t)wv * HID + lane;
    #pragma unroll 3
    for (int jj = 0; jj < 12; ++jj) {
      float4 s0 = *(const float4*)&skipT[wv][0][4 * jj];
      float4 s1 = *(const float4*)&skipT[wv][1][4 * jj];
      float4 s2 = *(const float4*)&skipT[wv][2][4 * jj];
      float4 s3 = *(const float4*)&skipT[wv][3][4 * jj];
      const float* s0a = (const float*)&s0;
      const float* s1a = (const float*)&s1;
      const float* s2a = (const float*)&s2;
      const float* s3a = (const float*)&s3;
      #pragma unroll
      for (int q = 0; q < 4; ++q) {
        const float wa = w5p[0];
        const float wb = w5p[64];
        a00 = fmaf(s0a[q], wa, a00); a01 = fmaf(s0a[q], wb, a01);
        a10 = fmaf(s1a[q], wa, a10); a11 = fmaf(s1a[q], wb, a11);
        a20 = fmaf(s2a[q], wa, a20); a21 = fmaf(s2a[q], wb, a21);
        a30 = fmaf(s3a[q], wa, a30); a31 = fmaf(s3a[q], wb, a31);
        w5p += 8 * HID;
      }
    }
    P2[wv][0][lane] = make_float2(a00, a01);
    P2[wv][1][lane] = make_float2(a10, a11);
    P2[wv][2][lane] = make_float2(a20, a21);
    P2[wv][3][lane] = make_float2(a30, a31);
    __syncthreads();

    // ---- finalize h, then y = h @ W6 + b6 ----
    {
      const int rr = tid >> 7;
      const int cc = tid & 127;       // cc>>6 is wave-uniform
      const int ll = cc & 63;
      float s = sb5[cc];
      if ((cc >> 6) == 0) {
        #pragma unroll
        for (int w8 = 0; w8 < 8; ++w8) s += P2[w8][rr][ll].x;
      } else {
        #pragma unroll
        for (int w8 = 0; w8 < 8; ++w8) s += P2[w8][rr][ll].y;
      }
      const float hv = fmaxf(s, 0.0f);
      float v = hv * sW6[cc];
      #pragma unroll
      for (int off = 32; off >= 1; off >>= 1) v += __shfl_xor(v, off);
      if ((tid & 63) == 0) wsum[tid >> 6] = v;
    }
    __syncthreads();
    if (tid < R) {
      const float y = wsum[2 * tid] + wsum[2 * tid + 1] + sb6v;
      prevy[tid] = y;
      out[(b0 + tid) * T_STEPS + t] = y;
    }
    __syncthreads();
  }
}

extern "C" void kernel_launch(void* const* d_in, const int* in_sizes, int n_in,
                              void* d_out, int out_size, void* d_ws, size_t ws_size,
                              hipStream_t stream) {
  const float* dec_feat = (const float*)d_in[0];
  const float* dec_init = (const float*)d_in[1];
  const float* enc      = (const float*)d_in[2];
  const float* W1 = (const float*)d_in[3];
  const float* b1 = (const float*)d_in[4];
  const float* W2 = (const float*)d_in[5];
  const float* b2 = (const float*)d_in[6];
  const float* W3 = (const float*)d_in[7];
  const float* W4 = (const float*)d_in[8];
  const float* b4 = (const float*)d_in[9];
  const float* W5 = (const float*)d_in[10];
  const float* b5 = (const float*)d_in[11];
  const float* W6 = (const float*)d_in[12];
  const float* b6 = (const float*)d_in[13];
  float* out = (float*)d_out;

  dim3 grid(B_TOT / R);
  dim3 block(BLK);
  decoder_v5_kernel<<<grid, block, 0, stream>>>(
      dec_feat, dec_init, enc, W1, b1, W2, b2, W3, W4, b4, W5, b5, W6, b6, out);
}

// Round 5
// 535.571 us; speedup vs baseline: 1.4106x; 1.3113x over previous
//
#include <hip/hip_runtime.h>

typedef _Float16 h16;
typedef _Float16 half8 __attribute__((ext_vector_type(8)));
typedef float floatx4 __attribute__((ext_vector_type(4)));

#define B_TOT 1024
#define T_STEPS 24
#define F 64          // FILTERS
#define C2 128        // 2*FILTERS
#define FEAT 15
#define L_ENC 168
#define HID 128
#define R 16          // batch rows per block = MFMA M tile
#define BLK 256       // 4 waves
#define FP 72         // padded row stride (h16) for 16-row activation tiles
#define W5_WS_ELEMS (12*8*64*8)   // f16 B-frag layout of W5

__device__ __forceinline__ floatx4 mfma16(half8 a, half8 b, floatx4 c) {
  return __builtin_amdgcn_mfma_f32_16x16x32_f16(a, b, c, 0, 0, 0);
}

// prep: W5 (384x128 f32, row-major) -> f16 B-frag layout in ws:
// idx = ((ktg*8 + nt)*64 + lane)*8 + j ; value = W5[ktg*32 + (lane>>4)*8 + j][nt*16 + (lane&15)]
__global__ void prep_w5(const float* __restrict__ gW5, h16* __restrict__ wsW5) {
  int t = blockIdx.x * 256 + threadIdx.x;     // 0..6143
  if (t >= 12 * 8 * 64) return;
  int lane = t & 63, nt = (t >> 6) & 7, ktg = t >> 9;
  int n  = nt * 16 + (lane & 15);
  int kb = ktg * 32 + (lane >> 4) * 8;
  half8 v;
  #pragma unroll
  for (int j = 0; j < 8; ++j) v[j] = (h16)gW5[(size_t)(kb + j) * C2 + n];
  *(half8*)&wsW5[(size_t)t * 8] = v;
}

// v6: MFMA f16 path. 16 rows/block, 4 waves; wave w owns n-tiles {w, w+4}.
// A-frag: A[m=lane&15][k=(lane>>4)*8+j]; B-frag: B[k=(lane>>4)*8+j][n=lane&15];
// C/D: col n=lane&15, row=(lane>>4)*4+reg.  (m89/m120-verified layouts)
__global__ __launch_bounds__(BLK) void decoder_v6(
    const float* __restrict__ dec_feat,   // (B,24,15)
    const float* __restrict__ dec_init,   // (B,1)
    const float* __restrict__ enc,        // (6,B,168,64)
    const float* __restrict__ gW1, const float* __restrict__ gb1,
    const float* __restrict__ gW2, const float* __restrict__ gb2,
    const float* __restrict__ gW3,
    const float* __restrict__ gW4, const float* __restrict__ gb4,
    const h16*  __restrict__ wsW5, const float* __restrict__ gb5,
    const float* __restrict__ gW6, const float* __restrict__ gb6,
    float* __restrict__ out)              // (B,24)
{
  __shared__ alignas(16) h16 sW2B[8][2][64][8];   // 16KB each: [nt][kt][lane][j]
  __shared__ alignas(16) h16 sW3B[8][2][64][8];
  __shared__ alignas(16) h16 sW4B[8][2][64][8];
  __shared__ alignas(16) h16 sW1B[4][64][8];      // 4KB (k>=16 zero-padded)
  __shared__ alignas(16) h16 ringL[31][R][FP];    // ~70KB: layer i base = 2^i-1 slots
  __shared__ alignas(16) h16 xH[R][FP];
  __shared__ alignas(16) float x32[R][F];         // fp32 master for residual stream
  __shared__ alignas(16) h16 gatedH[R][FP];
  __shared__ alignas(16) h16 skipH[R][FP];
  __shared__ alignas(16) h16 curH[R][40];         // k 0..31 used (16..31 zero), pad to 40
  __shared__ float sb1[F], sb2[C2], sb4[C2], sb5[HID], sW6v[HID];
  __shared__ float ypart[4][R];
  __shared__ float sb6;

  const int tid  = threadIdx.x;
  const int w    = tid >> 6;        // wave 0..3
  const int lane = tid & 63;
  const int m16  = lane & 15;
  const int q    = lane >> 4;
  const int q8   = q * 8;
  const int b0   = blockIdx.x * R;

  // ---- stage W2/W3/W4 B-frags (f16) ----
  #pragma unroll
  for (int it = 0; it < 4; ++it) {
    int tsk = tid + BLK * it;                 // 0..1023
    int ln = tsk & 63, kt = (tsk >> 6) & 1, nt = tsk >> 7;
    int n  = nt * 16 + (ln & 15);
    int kb = kt * 32 + (ln >> 4) * 8;
    half8 v2, v3, v4;
    #pragma unroll
    for (int j = 0; j < 8; ++j) {
      v2[j] = (h16)gW2[(kb + j) * C2 + n];
      v3[j] = (h16)gW3[(kb + j) * C2 + n];
      v4[j] = (h16)gW4[(kb + j) * C2 + n];
    }
    *(half8*)&sW2B[nt][kt][ln][0] = v2;
    *(half8*)&sW3B[nt][kt][ln][0] = v3;
    *(half8*)&sW4B[nt][kt][ln][0] = v4;
  }
  { // W1 B-frag: 256 tasks
    int nt = tid >> 6, ln = tid & 63;
    int n  = nt * 16 + (ln & 15);
    int kb = (ln >> 4) * 8;
    half8 v;
    #pragma unroll
    for (int j = 0; j < 8; ++j) {
      int k = kb + j;
      v[j] = (k < 16) ? (h16)gW1[k * F + n] : (h16)0.0f;
    }
    *(half8*)&sW1B[nt][ln][0] = v;
  }
  if (tid < F) sb1[tid] = gb1[tid];
  if (tid < C2) { sb2[tid] = gb2[tid]; sb4[tid] = gb4[tid]; sb5[tid] = gb5[tid]; sW6v[tid] = gW6[tid]; }
  if (tid == 0) sb6 = gb6[0];
  { int mm = tid >> 4, kk = 16 + (tid & 15); curH[mm][kk] = (h16)0.0f; }   // zero pad region
  if (tid < R * FEAT) { int mm = tid / FEAT, f = tid % FEAT;
    curH[mm][1 + f] = (h16)dec_feat[(b0 + mm) * (T_STEPS * FEAT) + f]; }
  if (tid < R) curH[tid][0] = (h16)dec_init[b0 + tid];
  __syncthreads();

  const int rbase[6] = {0, 1, 3, 7, 15, 0};   // ring slot base per layer (i<5)

  // stat A-frag loader: ring (LDS) if t>=d else encoder (global fp32 -> f16)
  auto loadStat = [&](half8* dst, int i, int d, int base, int t) {
    if (t >= d) {
      const h16* p = &ringL[base + (t & (d - 1))][m16][0];
      dst[0] = *(const half8*)(p + q8);
      dst[1] = *(const half8*)(p + 32 + q8);
    } else {
      const float* ep = enc + (((size_t)i * B_TOT + b0 + m16) * L_ENC + (L_ENC + t - d)) * F;
      #pragma unroll
      for (int kt = 0; kt < 2; ++kt) {
        float4 e0 = *(const float4*)(ep + kt * 32 + q8);
        float4 e1 = *(const float4*)(ep + kt * 32 + q8 + 4);
        half8 hv;
        hv[0] = (h16)e0.x; hv[1] = (h16)e0.y; hv[2] = (h16)e0.z; hv[3] = (h16)e0.w;
        hv[4] = (h16)e1.x; hv[5] = (h16)e1.y; hv[6] = (h16)e1.z; hv[7] = (h16)e1.w;
        dst[kt] = hv;
      }
    }
  };

  for (int t = 0; t < T_STEPS; ++t) {
    // ---- W1: x = tanh(cur @ W1 + b1), N=64 -> tile nt=w per wave ----
    half8 aCur = *(const half8*)&curH[m16][q8];
    half8 bW1  = *(const half8*)&sW1B[w][lane][0];
    floatx4 accX = {0.f, 0.f, 0.f, 0.f};
    accX = mfma16(aCur, bW1, accX);
    half8 stat[2];
    loadStat(stat, 0, 1, rbase[0], t);        // stat for dilation 0
    {
      int col = w * 16 + m16;                 // 0..63
      #pragma unroll
      for (int j = 0; j < 4; ++j) {
        int row = q * 4 + j;
        float v = tanhf(accX[j] + sb1[col]);
        x32[row][col] = v;
        xH[row][col]  = (h16)v;
      }
    }
    __syncthreads();                          // B1: xH ready

    floatx4 hAccA = {0.f, 0.f, 0.f, 0.f};     // W5 acc, nt=w
    floatx4 hAccB = {0.f, 0.f, 0.f, 0.f};     // W5 acc, nt=w+4

    #pragma unroll
    for (int i = 0; i < 6; ++i) {
      const int d = 1 << i;
      // x A-frags
      half8 xA0 = *(const half8*)&xH[m16][q8];
      half8 xA1 = *(const half8*)&xH[m16][32 + q8];
      // prefetch next dilation's stat
      half8 stN[2];
      if (i < 5) loadStat(stN, i + 1, d << 1, rbase[i + 1], t);
      // prefetch W5 B-frags for skip-chunk i (global, L2-hot; consumed after 2 barriers)
      half8 w5f[4];
      #pragma unroll
      for (int kt = 0; kt < 2; ++kt)
        #pragma unroll
        for (int nn = 0; nn < 2; ++nn)
          w5f[kt * 2 + nn] =
              *(const half8*)&wsW5[(size_t)((((2 * i + kt) * 8) + (w + 4 * nn)) * 64 + lane) * 8];

      // phase A: dil = stat@W2 + x@W3 (+b2)
      floatx4 aF = {0.f, 0.f, 0.f, 0.f}, aG = {0.f, 0.f, 0.f, 0.f};
      aF = mfma16(stat[0], *(const half8*)&sW2B[w][0][lane][0], aF);
      aF = mfma16(stat[1], *(const half8*)&sW2B[w][1][lane][0], aF);
      aF = mfma16(xA0,     *(const half8*)&sW3B[w][0][lane][0], aF);
      aF = mfma16(xA1,     *(const half8*)&sW3B[w][1][lane][0], aF);
      aG = mfma16(stat[0], *(const half8*)&sW2B[w + 4][0][lane][0], aG);
      aG = mfma16(stat[1], *(const half8*)&sW2B[w + 4][1][lane][0], aG);
      aG = mfma16(xA0,     *(const half8*)&sW3B[w + 4][0][lane][0], aG);
      aG = mfma16(xA1,     *(const half8*)&sW3B[w + 4][1][lane][0], aG);
      {
        int colF = w * 16 + m16;              // filter col (0..63); gate col = 64+colF
        #pragma unroll
        for (int j = 0; j < 4; ++j) {
          int row = q * 4 + j;
          float f = aF[j] + sb2[colF];
          float g = aG[j] + sb2[64 + colF];
          float gt = tanhf(f) / (1.0f + expf(-g));   // tanh(f)*sigmoid(g)
          gatedH[row][colF] = (h16)gt;
        }
      }
      __syncthreads();                        // B2a: gatedH ready

      // phase B: o = gated @ W4 + b4 ; skip cols 0..63 (nt w), residual 64..127 (nt w+4)
      half8 gA0 = *(const half8*)&gatedH[m16][q8];
      half8 gA1 = *(const half8*)&gatedH[m16][32 + q8];
      floatx4 oS = {0.f, 0.f, 0.f, 0.f}, oR = {0.f, 0.f, 0.f, 0.f};
      oS = mfma16(gA0, *(const half8*)&sW4B[w][0][lane][0], oS);
      oS = mfma16(gA1, *(const half8*)&sW4B[w][1][lane][0], oS);
      oR = mfma16(gA0, *(const half8*)&sW4B[w + 4][0][lane][0], oR);
      oR = mfma16(gA1, *(const half8*)&sW4B[w + 4][1][lane][0], oR);
      {
        int col = w * 16 + m16;               // 0..63
        #pragma unroll
        for (int j = 0; j < 4; ++j) {
          int row = q * 4 + j;
          float s = oS[j] + sb4[col];
          skipH[row][col] = (h16)fmaxf(s, 0.0f);
          float rr = oR[j] + sb4[64 + col];
          float xn = x32[row][col] + rr;      // fp32 master update (non-compounding rounding)
          x32[row][col] = xn;
          h16 hx = (h16)xn;
          xH[row][col] = hx;
          if (i < 5) ringL[rbase[i] + (t & (d - 1))][row][col] = hx;
        }
      }
      __syncthreads();                        // B2b: skipH/xH/ring ready

      // W5 skip-chunk i: h += skip_i @ W5[2i*32 .. ]
      half8 sk0 = *(const half8*)&skipH[m16][q8];
      half8 sk1 = *(const half8*)&skipH[m16][32 + q8];
      hAccA = mfma16(sk0, w5f[0], hAccA);
      hAccA = mfma16(sk1, w5f[2], hAccA);
      hAccB = mfma16(sk0, w5f[1], hAccB);
      hAccB = mfma16(sk1, w5f[3], hAccB);

      if (i < 5) { stat[0] = stN[0]; stat[1] = stN[1]; }
    }

    // ---- h = relu(hAcc + b5); y = h @ W6 + b6 ----
    {
      int colA = w * 16 + m16;                // 0..63 ; colB = 64+colA
      floatx4 vv;
      #pragma unroll
      for (int j = 0; j < 4; ++j) {
        float ha = fmaxf(hAccA[j] + sb5[colA], 0.0f);
        float hb = fmaxf(hAccB[j] + sb5[64 + colA], 0.0f);
        vv[j] = ha * sW6v[colA] + hb * sW6v[64 + colA];
      }
      #pragma unroll
      for (int off = 1; off < 16; off <<= 1) {
        #pragma unroll
        for (int j = 0; j < 4; ++j) vv[j] += __shfl_xor(vv[j], off, 16);
      }
      if (m16 == 0) {
        #pragma unroll
        for (int j = 0; j < 4; ++j) ypart[w][q * 4 + j] = vv[j];
      }
    }
    // stage next step's features (curH rows 1..15; safe: curH consumed at step top)
    if (t + 1 < T_STEPS && tid < R * FEAT) {
      int mm = tid / FEAT, f = tid % FEAT;
      curH[mm][1 + f] = (h16)dec_feat[(b0 + mm) * (T_STEPS * FEAT) + (t + 1) * FEAT + f];
    }
    __syncthreads();                          // B3: ypart ready
    if (tid < R) {
      float y = ypart[0][tid] + ypart[1][tid] + ypart[2][tid] + ypart[3][tid] + sb6;
      out[(b0 + tid) * T_STEPS + t] = y;
      curH[tid][0] = (h16)y;
    }
    __syncthreads();                          // B4: curH ready for next step
  }
}

extern "C" void kernel_launch(void* const* d_in, const int* in_sizes, int n_in,
                              void* d_out, int out_size, void* d_ws, size_t ws_size,
                              hipStream_t stream) {
  const float* dec_feat = (const float*)d_in[0];
  const float* dec_init = (const float*)d_in[1];
  const float* enc      = (const float*)d_in[2];
  const float* W1 = (const float*)d_in[3];
  const float* b1 = (const float*)d_in[4];
  const float* W2 = (const float*)d_in[5];
  const float* b2 = (const float*)d_in[6];
  const float* W3 = (const float*)d_in[7];
  const float* W4 = (const float*)d_in[8];
  const float* b4 = (const float*)d_in[9];
  const float* W5 = (const float*)d_in[10];
  const float* b5 = (const float*)d_in[11];
  const float* W6 = (const float*)d_in[12];
  const float* b6 = (const float*)d_in[13];
  float* out = (float*)d_out;
  h16* wsW5 = (h16*)d_ws;

  prep_w5<<<24, 256, 0, stream>>>(W5, wsW5);
  decoder_v6<<<dim3(B_TOT / R), dim3(BLK), 0, stream>>>(
      dec_feat, dec_init, enc, W1, b1, W2, b2, W3, W4, b4, wsW5, b5, W6, b6, out);
}